// Round 1
// baseline (146.707 us; speedup 1.0000x reference)
//
#include <hip/hip_runtime.h>
#include <hip/hip_bf16.h>

// B=4, C=256, N=HW=4096, Dqk=32.
// Round 9: attn was VALU-issue-bound (~150 VALU inst/wave-iter, VALUBusy 49%,
// true MFMA occupancy ~7%). Two structural sources: (1) the rolled loop's
// vcur<-vnext<-vnew register rotation (36 v_mov/iter), (2) per-iter 64-bit
// address materialization + min-clamp for 5 prefetch streams. Fix: manual x2
// unroll with two named register sets (rotation vanishes via renaming) and
// uniform-base + constant-lane-offset addressing (scalar pipe does all per-iter
// address work; prefetch tile index wraps &63 -> dead-but-valid tail loads).
// Carried from R8: packed-Vp coalesced B-frags, S^T trick, LDS-only barrier,
// XCD batch swizzle, packed-W qkv, no-max softmax.

#define N_PIX 4096
#define DQK   32
#define CCH   256
#define LOG2E 1.44269504088896f

typedef __attribute__((ext_vector_type(8))) _Float16 f16x8;
typedef __attribute__((ext_vector_type(4))) _Float16 f16x4;
typedef __attribute__((ext_vector_type(2))) _Float16 f16x2;
typedef __attribute__((ext_vector_type(8))) short    bf16x8;
typedef __attribute__((ext_vector_type(4))) short    bf16x4;
typedef __attribute__((ext_vector_type(4))) float    f32x4;

// LDS-only block barrier: waits lgkmcnt(0) but leaves vmcnt untouched.
__device__ inline void barrier_lds() {
    asm volatile("" ::: "memory");
    __builtin_amdgcn_s_waitcnt(0xc07f);   // vmcnt=63, expcnt=7, lgkmcnt=0
    __builtin_amdgcn_s_barrier();
    asm volatile("" ::: "memory");
}

__device__ inline short bf16bits(float f) {
    __hip_bfloat16 h = __float2bfloat16(f);
    return *(short*)&h;
}

// ---------------------------------------------------------------------------
// Kernel 0: pack Wq|Wk|Wv -> f16 A-fragments, lane-ordered (LOG2E folded into Wq).
// ---------------------------------------------------------------------------
__global__ __launch_bounds__(256) void wpack_kernel(
    const float* __restrict__ Wq, const float* __restrict__ Wk,
    const float* __restrict__ Wv, _Float16* __restrict__ Wp)
{
    const int tid   = threadIdx.x;
    const int wflat = blockIdx.x * 4 + (tid >> 6);   // 0..159
    const int lane  = tid & 63;
    const int L15   = lane & 15;
    const int quad  = lane >> 4;
    const int mt    = wflat >> 3;
    const int ks    = wflat & 7;
    const int m0    = mt * 16;

    const float* Wsrc; int row; float scale = 1.f;
    if (m0 < 32)      { Wsrc = Wq; row = m0 + L15;      scale = LOG2E; }
    else if (m0 < 64) { Wsrc = Wk; row = m0 - 32 + L15; }
    else              { Wsrc = Wv; row = m0 - 64 + L15; }

    const float* p = Wsrc + (size_t)row * 256 + ks * 32 + quad * 8;
    f16x8 h;
    #pragma unroll
    for (int j = 0; j < 8; ++j) h[j] = (_Float16)(p[j] * scale);
    *(f16x8*)(Wp + ((size_t)wflat * 64 + lane) * 8) = h;
}

// ---------------------------------------------------------------------------
// Kernel 1: QKV projection, f16 MFMA, packed W. Grid 512, 512 thr = 8 waves,
// 32-pixel tiles. V output goes through LDS transpose -> packed B-frag layout:
//   Vp[b][(n0>>5)*16 + cg16][lane(quad,L15)][j] = v[cg16*16+L15][n0 + quad*8+j]
// ---------------------------------------------------------------------------
__global__ __launch_bounds__(512, 4) void qkv_kernel(
    const float* __restrict__ x, const _Float16* __restrict__ Wp,
    const float* __restrict__ bq, const float* __restrict__ bk,
    const float* __restrict__ bv,
    _Float16* __restrict__ qo, _Float16* __restrict__ ko,
    __hip_bfloat16* __restrict__ vp)
{
    // shared: xT (32x264 f16 = 16.9KB) then reused as vst (256x40 bf16 = 20KB)
    __shared__ alignas(16) unsigned char shraw[256 * 40 * 2];
    _Float16       (*xT)[264] = (_Float16 (*)[264])shraw;
    __hip_bfloat16 (*vst)[40] = (__hip_bfloat16 (*)[40])shraw;

    const int idx = blockIdx.x;
    const int b   = (idx & 7) >> 1;
    const int n0  = (((idx >> 3) << 1) | (idx & 1)) * 32;
    const int tid = threadIdx.x;

    // stage x[256c][32n] -> xT[n][c] f16
    {
        const float* xb = x + (size_t)b * CCH * N_PIX;
        float4 ld[2][2];
        int c2s[2], n4s[2];
        #pragma unroll
        for (int pass = 0; pass < 2; ++pass) {
            const int flat = pass * 512 + tid;
            c2s[pass] = (flat >> 3) * 2;
            n4s[pass] = (flat & 7) * 4;
            ld[pass][0] = *(const float4*)(xb + (size_t)c2s[pass]       * N_PIX + n0 + n4s[pass]);
            ld[pass][1] = *(const float4*)(xb + (size_t)(c2s[pass] + 1) * N_PIX + n0 + n4s[pass]);
        }
        #pragma unroll
        for (int pass = 0; pass < 2; ++pass) {
            const float a[4] = {ld[pass][0].x, ld[pass][0].y, ld[pass][0].z, ld[pass][0].w};
            const float c[4] = {ld[pass][1].x, ld[pass][1].y, ld[pass][1].z, ld[pass][1].w};
            #pragma unroll
            for (int i = 0; i < 4; ++i)
                *(f16x2*)(&xT[n4s[pass] + i][c2s[pass]]) =
                    (f16x2){(_Float16)a[i], (_Float16)c[i]};
        }
    }
    __syncthreads();

    const int lane = tid & 63;
    const int wid  = tid >> 6;
    const int L15  = lane & 15;
    const int quad = lane >> 4;
    const int nf   = wid & 1;
    const int mtg  = wid >> 1;

    const f32x4 fz = {0.f, 0.f, 0.f, 0.f};
    f32x4 acc[5];
    #pragma unroll
    for (int mt = 0; mt < 5; ++mt) acc[mt] = fz;

    const _Float16* wpw = Wp + ((size_t)(mtg * 5) * 8 * 64 + lane) * 8;

    #pragma unroll
    for (int ks = 0; ks < 8; ++ks) {
        const f16x8 bfr = *(const f16x8*)(&xT[nf * 16 + L15][ks * 32 + quad * 8]);
        #pragma unroll
        for (int mt = 0; mt < 5; ++mt) {
            const f16x8 afr = *(const f16x8*)(wpw + (size_t)(mt * 8 + ks) * 512);
            acc[mt] = __builtin_amdgcn_mfma_f32_16x16x32_f16(afr, bfr, acc[mt], 0, 0, 0);
        }
    }

    // q/k epilogue (global, no LDS): C/D row = out-row (quad*4+r), col = pixel (L15)
    const int np = nf * 16 + L15;         // local pixel 0..31
    const int n  = n0 + np;
    #pragma unroll
    for (int mt = 0; mt < 5; ++mt) {
        const int m0 = (mtg * 5 + mt) * 16;
        const f32x4 a = acc[mt];
        if (m0 < 32) {
            const int mr = m0 + quad * 4;
            f16x4 h;
            #pragma unroll
            for (int r = 0; r < 4; ++r) h[r] = (_Float16)(a[r] + bq[mr + r] * LOG2E);
            *(f16x4*)(qo + ((size_t)b * N_PIX + n) * DQK + mr) = h;
        } else if (m0 < 64) {
            const int mr = m0 - 32 + quad * 4;
            f16x4 h;
            #pragma unroll
            for (int r = 0; r < 4; ++r) h[r] = (_Float16)(a[r] + bk[mr + r]);
            *(f16x4*)(ko + ((size_t)b * N_PIX + n) * DQK + mr) = h;
        }
    }

    __syncthreads();   // xT dead; vst aliases it

    // v -> LDS transpose buffer vst[ch][pix] (rows padded to 40 elems, 16B-aligned)
    #pragma unroll
    for (int mt = 0; mt < 5; ++mt) {
        const int m0 = (mtg * 5 + mt) * 16;
        if (m0 >= 64) {
            const int c = m0 - 64 + quad * 4;
            #pragma unroll
            for (int r = 0; r < 4; ++r)
                vst[c + r][np] = __float2bfloat16(acc[mt][r] + bv[c + r]);
        }
    }
    __syncthreads();

    // packed store: slot (cg16, lane'=(qd,l15)) -> one b128 LDS read + one 16B store
    {
        __hip_bfloat16* vpb = vp + (size_t)b * 2048 * 512 + (size_t)((n0 >> 5) * 16) * 512;
        #pragma unroll
        for (int s = 0; s < 2; ++s) {
            const int slot = s * 512 + tid;   // 0..1023
            const int cg16 = slot >> 6;
            const int ln   = slot & 63;
            const int qd   = ln >> 4;
            const int l15  = ln & 15;
            const bf16x8 val = *(const bf16x8*)(&vst[cg16 * 16 + l15][qd * 8]);
            *(bf16x8*)(vpb + ((size_t)cg16 * 64 + ln) * 8) = val;
        }
    }
}

// ---------------------------------------------------------------------------
// Kernel 2: attention. Grid 256 (XCD-swizzled), 1024 threads = 16 waves.
// S duty:  wave (qt=wid&3, kt=wid>>2): S^T = mfma(A=K, B=Q); one ds_write_b64.
// PV duty: wave (qp=wid&1, cg=wid>>1): 8 MFMA/iter from Ps + packed Vp.
// Main loop hand-unrolled x2: two register sets (even/odd tiles), zero
// rotation movs; all prefetch addresses are uniform-SGPR-base + constant
// lane offset (per-iter address work is SALU only). Prefetch index wraps &63
// -> tail loads are dead but valid.
// ---------------------------------------------------------------------------

// One unrolled body: uses tiles {V(J), K(J+1)}, reads Ps[PSRD], writes
// P(J+1) -> Ps[PSRD^1], prefetches V(J+2) and K(J+3) into the same regs.
#define ATTN_BODY(J, KR, VR, PSRD, DO_S)                                          \
  {                                                                               \
    const bool dos_ = (DO_S);                                                     \
    f32x4 s_ = fz;                                                                \
    if (dos_) s_ = __builtin_amdgcn_mfma_f32_16x16x32_f16(KR, aq, fz, 0, 0, 0);   \
    /* K prefetch for body J+2 (uniform base + lane offset) */                    \
    {                                                                             \
      const _Float16* kt_ = kb + (size_t)(((J) + 3) & 63) * (64 * DQK);           \
      KR = *(const f16x8*)(kt_ + koff);                                           \
    }                                                                             \
    /* PV: O += P(J) V(J) */                                                      \
    _Pragma("unroll")                                                             \
    for (int qq_ = 0; qq_ < 2; ++qq_) {                                           \
      _Pragma("unroll")                                                           \
      for (int kk_ = 0; kk_ < 2; ++kk_) {                                         \
        const bf16x8 ap_ = *(const bf16x8*)(                                      \
            &Ps[PSRD][(qp * 2 + qq_) * 16 + L15][kk_ * 32 + quad * 8]);           \
        oacc[qq_][0] = __builtin_amdgcn_mfma_f32_16x16x32_bf16(                   \
            ap_, VR[kk_][0], oacc[qq_][0], 0, 0, 0);                              \
        oacc[qq_][1] = __builtin_amdgcn_mfma_f32_16x16x32_bf16(                   \
            ap_, VR[kk_][1], oacc[qq_][1], 0, 0, 0);                              \
      }                                                                           \
    }                                                                             \
    /* V prefetch for body J+2 */                                                 \
    {                                                                             \
      const __hip_bfloat16* vt_ = vb + (size_t)(((J) + 2) & 63) * (2 * 16 * 512); \
      _Pragma("unroll")                                                           \
      for (int kk_ = 0; kk_ < 2; ++kk_)                                           \
        _Pragma("unroll")                                                         \
        for (int cf_ = 0; cf_ < 2; ++cf_)                                         \
          VR[kk_][cf_] = *(const bf16x8*)(vt_ + voff0 + kk_ * 8192 + cf_ * 512);  \
    }                                                                             \
    /* softmax-num + P write for tile J+1 */                                      \
    if (dos_) {                                                                   \
      bf16x4 pk_;                                                                 \
      _Pragma("unroll")                                                           \
      for (int r_ = 0; r_ < 4; ++r_) {                                            \
        const float p_ = exp2f(s_[r_]);                                           \
        psum += p_;                                                               \
        pk_[r_] = bf16bits(p_);                                                   \
      }                                                                           \
      *(bf16x4*)(&Ps[(PSRD) ^ 1][qt * 16 + L15][kt * 16 + quad * 4]) = pk_;       \
    }                                                                             \
    barrier_lds();                                                                \
  }

__global__ __launch_bounds__(1024, 1) void attn_kernel(
    const _Float16* __restrict__ qg,        // [B][N][32], q pre-scaled by log2e
    const _Float16* __restrict__ kg,        // [B][N][32]
    const __hip_bfloat16* __restrict__ vp,  // packed: [B][2048 chunks][64][8]
    float* __restrict__ out)                // [B][C][N]
{
    __shared__ alignas(16) __hip_bfloat16 Ps[2][64][72];   // P dbuf, rows 144B
    __shared__ float lsum[4][4][16];                       // [qt][kt][query]

    const int idx  = blockIdx.x;
    const int b    = (idx & 7) >> 1;
    const int n0   = (((idx >> 3) << 1) | (idx & 1)) * 64;
    const int tid  = threadIdx.x;
    const int wid  = tid >> 6;
    const int lane = tid & 63;
    const int L15  = lane & 15;
    const int quad = lane >> 4;
    const int qt   = wid & 3;    // S duty: q-tile
    const int kt   = wid >> 2;   // S duty: 16-key slice
    const int qp   = wid & 1;    // PV duty: q-pair {2qp, 2qp+1}
    const int cg   = wid >> 1;   // PV duty: 32-channel group
    const int c0   = cg * 32;

    const f32x4 fz = {0.f, 0.f, 0.f, 0.f};

    const f16x8 aq = *(const f16x8*)(qg + ((size_t)b * N_PIX + n0 + qt * 16 + L15) * DQK + quad * 8);

    f32x4 oacc[2][2];   // [qq][cf]
    #pragma unroll
    for (int qq = 0; qq < 2; ++qq)
        #pragma unroll
        for (int cf = 0; cf < 2; ++cf) oacc[qq][cf] = fz;
    float psum = 0.f;

    // uniform bases + per-lane constant offsets (elements)
    const _Float16* kb = kg + (size_t)b * N_PIX * DQK;
    const int koff  = (kt * 16 + L15) * DQK + quad * 8;
    const __hip_bfloat16* vb = vp + (size_t)b * 2048 * 512;
    const int voff0 = lane * 8 + cg * 2 * 512;   // kk adds 8192, cf adds 512

    // ---- prologue: K(1),K(2); V(0),V(1); P(0) from one-shot K(0)
    f16x8 kA = *(const f16x8*)(kb + (size_t)1 * 64 * DQK + koff);
    f16x8 kB = *(const f16x8*)(kb + (size_t)2 * 64 * DQK + koff);
    bf16x8 vA[2][2], vB[2][2];
    #pragma unroll
    for (int kk = 0; kk < 2; ++kk)
        #pragma unroll
        for (int cf = 0; cf < 2; ++cf) {
            vA[kk][cf] = *(const bf16x8*)(vb +                    voff0 + kk * 8192 + cf * 512);
            vB[kk][cf] = *(const bf16x8*)(vb + (size_t)16384 +    voff0 + kk * 8192 + cf * 512);
        }
    {
        const f16x8 k0f = *(const f16x8*)(kb + koff);
        const f32x4 s = __builtin_amdgcn_mfma_f32_16x16x32_f16(k0f, aq, fz, 0, 0, 0);
        bf16x4 pk;
        #pragma unroll
        for (int r = 0; r < 4; ++r) { const float p = exp2f(s[r]); psum += p; pk[r] = bf16bits(p); }
        *(bf16x4*)(&Ps[0][qt * 16 + L15][kt * 16 + quad * 4]) = pk;
    }
    barrier_lds();

    for (int it = 0; it < 64; it += 2) {
        ATTN_BODY(it,     kA, vA, 0, true);
        ATTN_BODY(it + 1, kB, vB, 1, it < 62);
    }

    // row-sums: reduce over quads holding same query, combine kt slices via LDS
    psum += __shfl_xor(psum, 16, 64);
    psum += __shfl_xor(psum, 32, 64);
    if (quad == 0) lsum[qt][kt][L15] = psum;
    __syncthreads();

    float* ob = out + (size_t)b * CCH * N_PIX;
    #pragma unroll
    for (int qq = 0; qq < 2; ++qq) {
        const int qtile = qp * 2 + qq;
        float inv_l[4];
        #pragma unroll
        for (int r = 0; r < 4; ++r) {
            const int q = quad * 4 + r;
            inv_l[r] = 1.f / (lsum[qtile][0][q] + lsum[qtile][1][q] +
                              lsum[qtile][2][q] + lsum[qtile][3][q]);
        }
        #pragma unroll
        for (int cf = 0; cf < 2; ++cf) {
            const int c = c0 + cf * 16 + L15;
            f32x4 o;
            #pragma unroll
            for (int r = 0; r < 4; ++r) o[r] = oacc[qq][cf][r] * inv_l[r];
            *(f32x4*)(ob + (size_t)c * N_PIX + n0 + qtile * 16 + quad * 4) = o;
        }
    }
}

// ---------------------------------------------------------------------------
extern "C" void kernel_launch(void* const* d_in, const int* in_sizes, int n_in,
                              void* d_out, int out_size, void* d_ws, size_t ws_size,
                              hipStream_t stream) {
    (void)in_sizes; (void)n_in; (void)out_size; (void)ws_size;
    const float* x  = (const float*)d_in[0];
    const float* Wq = (const float*)d_in[1];
    const float* bq = (const float*)d_in[2];
    const float* Wk = (const float*)d_in[3];
    const float* bk = (const float*)d_in[4];
    const float* Wv = (const float*)d_in[5];
    const float* bv = (const float*)d_in[6];

    // workspace: q 1MB | k 1MB | Vp 8MB | Wp 160KB
    _Float16* qb = (_Float16*)d_ws;
    _Float16* kb = qb + (size_t)4 * N_PIX * DQK;
    __hip_bfloat16* vpk = (__hip_bfloat16*)(kb + (size_t)4 * N_PIX * DQK);
    _Float16* wp = (_Float16*)(vpk + (size_t)4 * 2048 * 512);
    float* outp = (float*)d_out;

    wpack_kernel<<<40, 256, 0, stream>>>(Wq, Wk, Wv, wp);
    qkv_kernel<<<512, 512, 0, stream>>>(x, wp, bq, bk, bv, qb, kb, vpk);
    attn_kernel<<<256, 1024, 0, stream>>>(qb, kb, vpk, outp);
}